// Round 3
// baseline (278.979 us; speedup 1.0000x reference)
//
#include <hip/hip_runtime.h>

#define NBINS 256
#define NCH 3
#define HSIZE (NBINS * NCH)   // 768
#define NWAVE 4               // private histogram copies per block (one per wave)
#define TPB 256
#define BLOCKS 2048
#define RBLOCKS 32            // reduce kernel blocks (each sums BLOCKS/RBLOCKS rows)

typedef float f4 __attribute__((ext_vector_type(4)));

__global__ __launch_bounds__(TPB) void hist_kernel(const float* __restrict__ in,
                                                   unsigned int* __restrict__ ws,
                                                   int n) {
    __shared__ unsigned int lds[NWAVE][HSIZE];

    const int tid = threadIdx.x;

    // zero LDS (3072 words / 256 threads = 12 each)
    unsigned int* flat = &lds[0][0];
    #pragma unroll
    for (int i = 0; i < NWAVE * HSIZE / TPB; ++i)
        flat[tid + i * TPB] = 0u;
    __syncthreads();

    unsigned int* h = lds[tid >> 6];

    // Each thread owns groups of 12 consecutive floats (= 4 RGB pixels = 3 float4).
    // Group base element 12*g is always channel 0 -> channel pattern is STATIC:
    //   f4 a (elems 0..3):  ch 0,1,2,0
    //   f4 b (elems 4..7):  ch 1,2,0,1
    //   f4 c (elems 8..11): ch 2,0,1,2
    // Plain (cached) loads: the 3 overlapping 48B-strided loads share cache
    // lines via L1 — do NOT use nontemporal here.
    const long long ngrp   = n / 12;
    const long long stride = (long long)gridDim.x * TPB;
    const f4* __restrict__ in4 = (const f4*)in;

    #pragma unroll 2
    for (long long g = (long long)blockIdx.x * TPB + tid; g < ngrp; g += stride) {
        const f4* p = in4 + 3 * g;
        f4 a = p[0];
        f4 b = p[1];
        f4 c = p[2];

        int a0 = min(max((int)(a.x * 256.0f), 0), 255);
        int a1 = min(max((int)(a.y * 256.0f), 0), 255);
        int a2 = min(max((int)(a.z * 256.0f), 0), 255);
        int a3 = min(max((int)(a.w * 256.0f), 0), 255);
        int b0 = min(max((int)(b.x * 256.0f), 0), 255);
        int b1 = min(max((int)(b.y * 256.0f), 0), 255);
        int b2 = min(max((int)(b.z * 256.0f), 0), 255);
        int b3 = min(max((int)(b.w * 256.0f), 0), 255);
        int c0 = min(max((int)(c.x * 256.0f), 0), 255);
        int c1 = min(max((int)(c.y * 256.0f), 0), 255);
        int c2 = min(max((int)(c.z * 256.0f), 0), 255);
        int c3 = min(max((int)(c.w * 256.0f), 0), 255);

        atomicAdd(&h[0 * NBINS + a0], 1u);
        atomicAdd(&h[1 * NBINS + a1], 1u);
        atomicAdd(&h[2 * NBINS + a2], 1u);
        atomicAdd(&h[0 * NBINS + a3], 1u);
        atomicAdd(&h[1 * NBINS + b0], 1u);
        atomicAdd(&h[2 * NBINS + b1], 1u);
        atomicAdd(&h[0 * NBINS + b2], 1u);
        atomicAdd(&h[1 * NBINS + b3], 1u);
        atomicAdd(&h[2 * NBINS + c0], 1u);
        atomicAdd(&h[0 * NBINS + c1], 1u);
        atomicAdd(&h[1 * NBINS + c2], 1u);
        atomicAdd(&h[2 * NBINS + c3], 1u);
    }

    // scalar tail (n not divisible by 12) — only block 0
    if (blockIdx.x == 0) {
        for (long long e = ngrp * 12 + tid; e < n; e += TPB) {
            float x = in[e];
            int bin = min(max((int)(x * 256.0f), 0), 255);
            int ch = (int)(e % 3);
            atomicAdd(&h[ch * NBINS + bin], 1u);
        }
    }

    __syncthreads();

    // flush: sum the 4 wave copies, NON-atomic coalesced store to this
    // block's private row of ws. 2048 x 768 u32 = 6 MB streaming writes.
    unsigned int* dst = ws + (long long)blockIdx.x * HSIZE;
    #pragma unroll
    for (int i = 0; i < HSIZE / TPB; ++i) {
        int idx = tid + i * TPB;
        dst[idx] = lds[0][idx] + lds[1][idx] + lds[2][idx] + lds[3][idx];
    }
}

// Sum the 2048 x 768 partial matrix column-wise; each block handles
// BLOCKS/RBLOCKS rows, then float-atomicAdds the normalized partial into
// d_out (pre-zeroed). out layout: [bin, channel] -> out[bin*3 + c].
__global__ __launch_bounds__(TPB) void reduce_kernel(const unsigned int* __restrict__ ws,
                                                     float* __restrict__ out,
                                                     float inv_total) {
    const int tid = threadIdx.x;
    const int row0 = blockIdx.x * (BLOCKS / RBLOCKS);

    unsigned int s0 = 0, s1 = 0, s2 = 0;
    for (int r = 0; r < BLOCKS / RBLOCKS; ++r) {
        const unsigned int* rowp = ws + (long long)(row0 + r) * HSIZE;
        s0 += rowp[tid];
        s1 += rowp[tid + 256];
        s2 += rowp[tid + 512];
    }
    // col idx -> (c, bin): c = idx>>8, bin = idx&255 ; out[bin*3 + c]
    {
        int idx = tid;            // c=0
        atomicAdd(&out[(idx & 255) * 3 + (idx >> 8)], (float)s0 * inv_total);
    }
    {
        int idx = tid + 256;      // c=1
        atomicAdd(&out[(idx & 255) * 3 + (idx >> 8)], (float)s1 * inv_total);
    }
    {
        int idx = tid + 512;      // c=2
        atomicAdd(&out[(idx & 255) * 3 + (idx >> 8)], (float)s2 * inv_total);
    }
}

extern "C" void kernel_launch(void* const* d_in, const int* in_sizes, int n_in,
                              void* d_out, int out_size, void* d_ws, size_t ws_size,
                              hipStream_t stream) {
    const float* in = (const float*)d_in[0];
    const int n = in_sizes[0];
    unsigned int* ws = (unsigned int*)d_ws;
    float* out = (float*)d_out;

    hipMemsetAsync(out, 0, HSIZE * sizeof(float), stream);
    hist_kernel<<<BLOCKS, TPB, 0, stream>>>(in, ws, n);
    reduce_kernel<<<RBLOCKS, TPB, 0, stream>>>(ws, out, 1.0f / (float)(n / NCH));
}